// Round 9
// baseline (635.572 us; speedup 1.0000x reference)
//
#include <hip/hip_runtime.h>
#include <hip/hip_fp16.h>

#define GRID_N 4096
#define NTHREADS 256
#define QSTRIDE 4096   // quads per row (pow2 for cheap addressing)
#define QROWS 4095

typedef float f32x4 __attribute__((ext_vector_type(4)));
typedef unsigned short u16x4 __attribute__((ext_vector_type(4)));
typedef unsigned short u16x8 __attribute__((ext_vector_type(8)));

__device__ __forceinline__ float h2f(unsigned short u) {
    union { __half h; unsigned short u; } cv;
    cv.u = u;
    return __half2float(cv.h);
}
__device__ __forceinline__ unsigned short f2h(float f) {
    union { __half h; unsigned short u; } cv;
    cv.h = __float2half(f);
    return cv.u;
}

__global__ void zero_loss_kernel(float* out) {
    if (threadIdx.x == 0) out[0] = 0.0f;
}

// Build fp16 quad grid: Q[r][c] = (v[r][c], v[r+1][c], v[r][c+1], v[r+1][c+1])
// packed as 4 fp16 in 8B, so ONE 8B load per point fetches the whole stencil.
// One block per row r; rows staged in LDS with coalesced 16B loads.
__global__ __launch_bounds__(NTHREADS) void build_quad_kernel(
    const float* __restrict__ sdf, unsigned short* __restrict__ Q)
{
    __shared__ float r0[GRID_N], r1[GRID_N];
    const int r = blockIdx.x;            // 0..4094
    const int t = threadIdx.x;

    const f32x4* row0 = (const f32x4*)(sdf + (size_t)r * GRID_N);
    const f32x4* row1 = (const f32x4*)(sdf + (size_t)(r + 1) * GRID_N);
    f32x4* l0 = (f32x4*)r0;
    f32x4* l1 = (f32x4*)r1;
    for (int j = t; j < GRID_N / 4; j += NTHREADS) {
        l0[j] = __builtin_nontemporal_load(&row0[j]);
        l1[j] = __builtin_nontemporal_load(&row1[j]);
    }
    __syncthreads();

    // thread t writes quads c = 16t .. 16t+15, two quads per 16B store
    u16x8* qrow = (u16x8*)(Q + (size_t)r * QSTRIDE * 4);
#pragma unroll
    for (int j = 0; j < 8; ++j) {
        int c0 = t * 16 + j * 2;
        int c1 = c0 + 1;
        int c0n = min(c0 + 1, GRID_N - 1);
        int c1n = min(c1 + 1, GRID_N - 1);
        u16x8 v;
        v[0] = f2h(r0[c0]);  v[1] = f2h(r1[c0]);
        v[2] = f2h(r0[c0n]); v[3] = f2h(r1[c0n]);
        v[4] = f2h(r0[c1]);  v[5] = f2h(r1[c1]);
        v[6] = f2h(r0[c1n]); v[7] = f2h(r1[c1n]);
        __builtin_nontemporal_store(v, &qrow[t * 8 + j]);
    }
}

__global__ __launch_bounds__(NTHREADS) void sdf_bilinear_quad_kernel(
    const float* __restrict__ x,
    const float* __restrict__ y,
    const unsigned short* __restrict__ Q,
    float* __restrict__ out,
    int n8)  // number of 8-point groups
{
    const int tid = blockIdx.x * blockDim.x + threadIdx.x;
    const int stride = gridDim.x * blockDim.x;
    float lsum = 0.0f;

    const f32x4* x4 = (const f32x4*)x;
    const f32x4* y4 = (const f32x4*)y;
    const u16x4* Qv = (const u16x4*)Q;
    float* vals_out = out + 1;

    for (int i = tid; i < n8; i += stride) {
        const int g0 = 2 * i, g1 = 2 * i + 1;
        f32x4 xa = __builtin_nontemporal_load(&x4[g0]);
        f32x4 xb = __builtin_nontemporal_load(&x4[g1]);
        f32x4 ya = __builtin_nontemporal_load(&y4[g0]);
        f32x4 yb = __builtin_nontemporal_load(&y4[g1]);
        float xs[8] = {xa.x, xa.y, xa.z, xa.w, xb.x, xb.y, xb.z, xb.w};
        float ys[8] = {ya.x, ya.y, ya.z, ya.w, yb.x, yb.y, yb.z, yb.w};

        u16x4 q[8];
        float t[8], u[8];
#pragma unroll
        for (int k = 0; k < 8; ++k) {
            float xi = xs[k];
            float yi = ys[k];
            int x1 = min((int)xi, GRID_N - 2);   // inputs >= 0
            int y1 = min((int)yi, GRID_N - 2);
            t[k] = xi - (float)x1;
            u[k] = yi - (float)y1;
            q[k] = Qv[((size_t)x1 << 12) | (size_t)y1];  // ONE 8B gather per point
        }

        float res[8];
#pragma unroll
        for (int k = 0; k < 8; ++k) {
            float v11 = h2f(q[k][0]);
            float v21 = h2f(q[k][1]);
            float v12 = h2f(q[k][2]);
            float v22 = h2f(q[k][3]);
            float a = v11 + t[k] * (v21 - v11);
            float b = v12 + t[k] * (v22 - v12);
            float val = a + u[k] * (b - a);
            val = fminf(0.0f, fmaxf(-1000.0f, val));
            res[k] = val;
            lsum += val;
        }

        int base = g0 * 4;
#pragma unroll
        for (int k = 0; k < 8; ++k)
            __builtin_nontemporal_store(res[k], &vals_out[base + k]);
    }

#pragma unroll
    for (int off = 32; off > 0; off >>= 1)
        lsum += __shfl_down(lsum, off);

    __shared__ float wsum[NTHREADS / 64];
    const int lane = threadIdx.x & 63;
    const int wid = threadIdx.x >> 6;
    if (lane == 0) wsum[wid] = lsum;
    __syncthreads();
    if (threadIdx.x == 0) {
        float bsum = 0.0f;
#pragma unroll
        for (int w = 0; w < NTHREADS / 64; ++w) bsum += wsum[w];
        atomicAdd(out, bsum);
    }
}

// ---------------- direct fallback (no workspace needed) ----------------
__global__ __launch_bounds__(NTHREADS) void sdf_bilinear_direct_kernel(
    const float* __restrict__ x,
    const float* __restrict__ y,
    const float* __restrict__ sdf,
    float* __restrict__ out,
    int n4)
{
    const int tid = blockIdx.x * blockDim.x + threadIdx.x;
    const int stride = gridDim.x * blockDim.x;
    float lsum = 0.0f;
    const f32x4* x4 = (const f32x4*)x;
    const f32x4* y4 = (const f32x4*)y;
    float* vals_out = out + 1;

    for (int i = tid; i < n4; i += stride) {
        f32x4 xv = x4[i];
        f32x4 yv = y4[i];
        float xs[4] = {xv.x, xv.y, xv.z, xv.w};
        float ys[4] = {yv.x, yv.y, yv.z, yv.w};
        float res[4];
#pragma unroll
        for (int k = 0; k < 4; ++k) {
            float xi = xs[k], yi = ys[k];
            int x1 = min((int)xi, GRID_N - 2);
            int y1 = min((int)yi, GRID_N - 2);
            float t = xi - (float)x1;
            float u = yi - (float)y1;
            const float* r1 = sdf + ((size_t)x1 << 12);
            const float* r2 = r1 + GRID_N;
            float v11 = r1[y1], v12 = r1[y1 + 1];
            float v21 = r2[y1], v22 = r2[y1 + 1];
            float a = v11 + t * (v21 - v11);
            float b = v12 + t * (v22 - v12);
            float val = a + u * (b - a);
            val = fminf(0.0f, fmaxf(-1000.0f, val));
            res[k] = val;
            lsum += val;
        }
        int base = i * 4;
        vals_out[base + 0] = res[0];
        vals_out[base + 1] = res[1];
        vals_out[base + 2] = res[2];
        vals_out[base + 3] = res[3];
    }

#pragma unroll
    for (int off = 32; off > 0; off >>= 1)
        lsum += __shfl_down(lsum, off);

    __shared__ float wsum[NTHREADS / 64];
    const int lane = threadIdx.x & 63;
    const int wid = threadIdx.x >> 6;
    if (lane == 0) wsum[wid] = lsum;
    __syncthreads();
    if (threadIdx.x == 0) {
        float bsum = 0.0f;
#pragma unroll
        for (int w = 0; w < NTHREADS / 64; ++w) bsum += wsum[w];
        atomicAdd(out, bsum);
    }
}

extern "C" void kernel_launch(void* const* d_in, const int* in_sizes, int n_in,
                              void* d_out, int out_size, void* d_ws, size_t ws_size,
                              hipStream_t stream) {
    const float* x = (const float*)d_in[0];
    const float* y = (const float*)d_in[1];
    const float* sdf = (const float*)d_in[2];
    float* out = (float*)d_out;
    int n = in_sizes[0];
    int n4 = n >> 2;
    int n8 = n >> 3;

    zero_loss_kernel<<<1, 64, 0, stream>>>(out);

    const size_t quad_bytes = (size_t)QROWS * QSTRIDE * 4 * sizeof(unsigned short); // 134.2 MB

    if (ws_size >= quad_bytes) {
        unsigned short* Q = (unsigned short*)d_ws;
        build_quad_kernel<<<QROWS, NTHREADS, 0, stream>>>(sdf, Q);
        int nblocks = (n8 + NTHREADS - 1) / NTHREADS;  // one 8-pt group per thread
        sdf_bilinear_quad_kernel<<<nblocks, NTHREADS, 0, stream>>>(x, y, Q, out, n8);
    } else {
        sdf_bilinear_direct_kernel<<<2048, NTHREADS, 0, stream>>>(x, y, sdf, out, n4);
    }
}

// Round 10
// 554.993 us; speedup vs baseline: 1.1452x; 1.1452x over previous
//
#include <hip/hip_runtime.h>
#include <hip/hip_fp16.h>

#define GRID_N 4096
#define NTHREADS 256

typedef float f32x4 __attribute__((ext_vector_type(4)));
typedef float f32x2 __attribute__((ext_vector_type(2)));
typedef unsigned short u16x4 __attribute__((ext_vector_type(4)));
typedef unsigned short u16x8 __attribute__((ext_vector_type(8)));

__device__ __forceinline__ float h2f(unsigned short u) {
    union { __half h; unsigned short u; } cv;
    cv.u = u;
    return __half2float(cv.h);
}
__device__ __forceinline__ unsigned short f2h(float f) {
    union { __half h; unsigned short u; } cv;
    cv.h = __float2half(f);
    return cv.u;
}

__global__ void zero_loss_kernel(float* out) {
    if (threadIdx.x == 0) out[0] = 0.0f;
}

// ---------------- Phase 1: fp16 grid H[4096][4096] (32 MB) ----------------
__global__ __launch_bounds__(NTHREADS) void build_h_kernel(
    const float* __restrict__ sdf, unsigned short* __restrict__ H)
{
    const int tid = blockIdx.x * blockDim.x + threadIdx.x;
    const int stride = gridDim.x * blockDim.x;
    const f32x4* s4 = (const f32x4*)sdf;
    u16x4* h4 = (u16x4*)H;
    const int n4 = (GRID_N * GRID_N) / 4;
    for (int i = tid; i < n4; i += stride) {
        f32x4 v = __builtin_nontemporal_load(&s4[i]);
        u16x4 h = { f2h(v.x), f2h(v.y), f2h(v.z), f2h(v.w) };
        h4[i] = h;   // normal store (cacheable)
    }
}

// ---------------- Phase 2: pack records {y1,x1,t,u} 8B each ----------------
__global__ __launch_bounds__(NTHREADS) void pack_rec_kernel(
    const float* __restrict__ x, const float* __restrict__ y,
    unsigned short* __restrict__ R, int n4)   // n4 = npts/4
{
    const int tid = blockIdx.x * blockDim.x + threadIdx.x;
    const int stride = gridDim.x * blockDim.x;
    const f32x4* x4 = (const f32x4*)x;
    const f32x4* y4 = (const f32x4*)y;
    u16x8* r8 = (u16x8*)R;
    for (int i = tid; i < n4; i += stride) {
        f32x4 xv = __builtin_nontemporal_load(&x4[i]);
        f32x4 yv = __builtin_nontemporal_load(&y4[i]);
        float xs[4] = {xv.x, xv.y, xv.z, xv.w};
        float ys[4] = {yv.x, yv.y, yv.z, yv.w};
        unsigned short f[16];
#pragma unroll
        for (int k = 0; k < 4; ++k) {
            int x1 = min((int)xs[k], GRID_N - 2);
            int y1 = min((int)ys[k], GRID_N - 2);
            f[4*k+0] = (unsigned short)y1;
            f[4*k+1] = (unsigned short)x1;
            f[4*k+2] = f2h(xs[k] - (float)x1);
            f[4*k+3] = f2h(ys[k] - (float)y1);
        }
        u16x8 r0 = {f[0],f[1],f[2],f[3],f[4],f[5],f[6],f[7]};
        u16x8 r1 = {f[8],f[9],f[10],f[11],f[12],f[13],f[14],f[15]};
        r8[2*i]   = r0;   // normal stores -> LLC-resident for the 8 re-reads
        r8[2*i+1] = r1;
    }
}

// ---------------- Phase 3: XCD-slab main kernel ----------------
// vslab = blockIdx&7 (round-robin XCD); each slab's blocks scan ALL records,
// process only points with x1 in [512*vslab, 512*vslab+512). The 4-MB fp16
// slab of H stays resident in that XCD's L2 -> gathers are L2 hits.
__global__ __launch_bounds__(NTHREADS) void sdf_slab_kernel(
    const unsigned short* __restrict__ R,
    const unsigned short* __restrict__ H,
    float* __restrict__ out,
    int nrec2)   // number of u16x8 units (= npts/2)
{
    const int vslab = blockIdx.x & 7;
    const int rank  = blockIdx.x >> 3;
    const int nrank = gridDim.x >> 3;
    const int stid  = rank * NTHREADS + threadIdx.x;
    const int sthreads = nrank * NTHREADS;
    float lsum = 0.0f;
    const u16x8* R8 = (const u16x8*)R;
    float* vals_out = out + 1;

    for (int g = stid; g < nrec2; g += sthreads) {
        u16x8 rr = R8[g];   // 2 records, coalesced, LLC-served
#pragma unroll
        for (int k = 0; k < 2; ++k) {
            int y1 = rr[4*k+0];
            int x1 = rr[4*k+1];
            if ((x1 >> 9) != vslab) continue;
            float t = h2f(rr[4*k+2]);
            float u = h2f(rr[4*k+3]);
            unsigned off0 = ((unsigned)x1 << 12) + (unsigned)y1;
            unsigned off1 = off0 + GRID_N;
            // two aligned dwords per row cover cols y1, y1+1 for any parity
            unsigned d0  = *(const unsigned*)(H + (off0 & ~1u));
            unsigned d0b = *(const unsigned*)(H + ((off0 + 1) & ~1u));
            unsigned d1  = *(const unsigned*)(H + (off1 & ~1u));
            unsigned d1b = *(const unsigned*)(H + ((off1 + 1) & ~1u));
            bool odd = (off0 & 1u) != 0;
            unsigned short v11 = odd ? (unsigned short)(d0 >> 16) : (unsigned short)d0;
            unsigned short v12 = odd ? (unsigned short)d0b        : (unsigned short)(d0 >> 16);
            unsigned short v21 = odd ? (unsigned short)(d1 >> 16) : (unsigned short)d1;
            unsigned short v22 = odd ? (unsigned short)d1b        : (unsigned short)(d1 >> 16);
            float f11 = h2f(v11), f21 = h2f(v21), f12 = h2f(v12), f22 = h2f(v22);
            float a = f11 + t * (f21 - f11);
            float b = f12 + t * (f22 - f12);
            float val = a + u * (b - a);
            val = fminf(0.0f, fmaxf(-1000.0f, val));
            lsum += val;
            vals_out[2 * g + k] = val;   // original order; partials merge in L2/LLC
        }
    }

#pragma unroll
    for (int off = 32; off > 0; off >>= 1)
        lsum += __shfl_down(lsum, off);

    __shared__ float wsum[NTHREADS / 64];
    const int lane = threadIdx.x & 63;
    const int wid = threadIdx.x >> 6;
    if (lane == 0) wsum[wid] = lsum;
    __syncthreads();
    if (threadIdx.x == 0) {
        float bsum = 0.0f;
#pragma unroll
        for (int w = 0; w < NTHREADS / 64; ++w) bsum += wsum[w];
        atomicAdd(out, bsum);
    }
}

// ---------------- p7 fallback (R8 path, proven at ws>=153.3 MB) ----------------
#define P7_BLOCKS 585
#define P7_ROW_FLOATS (P7_BLOCKS * 16)
#define P7_ROWS (GRID_N - 1)

__global__ __launch_bounds__(NTHREADS) void build_p7_kernel(
    const float* __restrict__ sdf, float* __restrict__ P7)
{
    const int t = blockIdx.x * blockDim.x + threadIdx.x;
    const int r = blockIdx.y;
    if (t >= P7_BLOCKS * 8) return;
    const int b = t >> 3;
    const int s = t & 7;
    int c = 7 * b + s;
    float a = __builtin_nontemporal_load(&sdf[(size_t)r * GRID_N + c]);
    float d = __builtin_nontemporal_load(&sdf[(size_t)(r + 1) * GRID_N + c]);
    f32x2* row = (f32x2*)(P7 + (size_t)r * P7_ROW_FLOATS);
    f32x2 v = {a, d};
    row[t] = v;
}

__global__ __launch_bounds__(NTHREADS) void sdf_bilinear_p7_kernel(
    const float* __restrict__ x,
    const float* __restrict__ y,
    const float* __restrict__ P7,
    float* __restrict__ out,
    int n8)
{
    const int tid = blockIdx.x * blockDim.x + threadIdx.x;
    const int stride = gridDim.x * blockDim.x;
    float lsum = 0.0f;
    const f32x4* x4 = (const f32x4*)x;
    const f32x4* y4 = (const f32x4*)y;
    float* vals_out = out + 1;

    for (int i = tid; i < n8; i += stride) {
        const int g0 = 2 * i, g1 = 2 * i + 1;
        f32x4 xa = __builtin_nontemporal_load(&x4[g0]);
        f32x4 xb = __builtin_nontemporal_load(&x4[g1]);
        f32x4 ya = __builtin_nontemporal_load(&y4[g0]);
        f32x4 yb = __builtin_nontemporal_load(&y4[g1]);
        float xs[8] = {xa.x, xa.y, xa.z, xa.w, xb.x, xb.y, xb.z, xb.w};
        float ys[8] = {ya.x, ya.y, ya.z, ya.w, yb.x, yb.y, yb.z, yb.w};
        f32x2 lo[8], hi[8];
        float t[8], u[8];
#pragma unroll
        for (int k = 0; k < 8; ++k) {
            float xi = xs[k], yi = ys[k];
            int x1 = min((int)xi, GRID_N - 2);
            int y1 = min((int)yi, GRID_N - 2);
            t[k] = xi - (float)x1;
            u[k] = yi - (float)y1;
            int b = (y1 * 37450) >> 18;
            int s = y1 - 7 * b;
            const f32x2* blk = (const f32x2*)(P7 + (size_t)x1 * P7_ROW_FLOATS) + (b << 3) + s;
            lo[k] = blk[0];
            hi[k] = blk[1];
        }
        float res[8];
#pragma unroll
        for (int k = 0; k < 8; ++k) {
            float v11 = lo[k].x, v21 = lo[k].y;
            float v12 = hi[k].x, v22 = hi[k].y;
            float a = v11 + t[k] * (v21 - v11);
            float b2 = v12 + t[k] * (v22 - v12);
            float val = a + u[k] * (b2 - a);
            val = fminf(0.0f, fmaxf(-1000.0f, val));
            res[k] = val;
            lsum += val;
        }
        int base = g0 * 4;
#pragma unroll
        for (int k = 0; k < 8; ++k)
            __builtin_nontemporal_store(res[k], &vals_out[base + k]);
    }

#pragma unroll
    for (int off = 32; off > 0; off >>= 1)
        lsum += __shfl_down(lsum, off);

    __shared__ float wsum[NTHREADS / 64];
    const int lane = threadIdx.x & 63;
    const int wid = threadIdx.x >> 6;
    if (lane == 0) wsum[wid] = lsum;
    __syncthreads();
    if (threadIdx.x == 0) {
        float bsum = 0.0f;
#pragma unroll
        for (int w = 0; w < NTHREADS / 64; ++w) bsum += wsum[w];
        atomicAdd(out, bsum);
    }
}

// ---------------- direct fallback (no workspace) ----------------
__global__ __launch_bounds__(NTHREADS) void sdf_bilinear_direct_kernel(
    const float* __restrict__ x,
    const float* __restrict__ y,
    const float* __restrict__ sdf,
    float* __restrict__ out,
    int n4)
{
    const int tid = blockIdx.x * blockDim.x + threadIdx.x;
    const int stride = gridDim.x * blockDim.x;
    float lsum = 0.0f;
    const f32x4* x4 = (const f32x4*)x;
    const f32x4* y4 = (const f32x4*)y;
    float* vals_out = out + 1;

    for (int i = tid; i < n4; i += stride) {
        f32x4 xv = x4[i];
        f32x4 yv = y4[i];
        float xs[4] = {xv.x, xv.y, xv.z, xv.w};
        float ys[4] = {yv.x, yv.y, yv.z, yv.w};
        float res[4];
#pragma unroll
        for (int k = 0; k < 4; ++k) {
            float xi = xs[k], yi = ys[k];
            int x1 = min((int)xi, GRID_N - 2);
            int y1 = min((int)yi, GRID_N - 2);
            float t = xi - (float)x1;
            float u = yi - (float)y1;
            const float* r1 = sdf + ((size_t)x1 << 12);
            const float* r2 = r1 + GRID_N;
            float v11 = r1[y1], v12 = r1[y1 + 1];
            float v21 = r2[y1], v22 = r2[y1 + 1];
            float a = v11 + t * (v21 - v11);
            float b = v12 + t * (v22 - v12);
            float val = a + u * (b - a);
            val = fminf(0.0f, fmaxf(-1000.0f, val));
            res[k] = val;
            lsum += val;
        }
        int base = i * 4;
        vals_out[base + 0] = res[0];
        vals_out[base + 1] = res[1];
        vals_out[base + 2] = res[2];
        vals_out[base + 3] = res[3];
    }

#pragma unroll
    for (int off = 32; off > 0; off >>= 1)
        lsum += __shfl_down(lsum, off);

    __shared__ float wsum[NTHREADS / 64];
    const int lane = threadIdx.x & 63;
    const int wid = threadIdx.x >> 6;
    if (lane == 0) wsum[wid] = lsum;
    __syncthreads();
    if (threadIdx.x == 0) {
        float bsum = 0.0f;
#pragma unroll
        for (int w = 0; w < NTHREADS / 64; ++w) bsum += wsum[w];
        atomicAdd(out, bsum);
    }
}

extern "C" void kernel_launch(void* const* d_in, const int* in_sizes, int n_in,
                              void* d_out, int out_size, void* d_ws, size_t ws_size,
                              hipStream_t stream) {
    const float* x = (const float*)d_in[0];
    const float* y = (const float*)d_in[1];
    const float* sdf = (const float*)d_in[2];
    float* out = (float*)d_out;
    int n = in_sizes[0];
    int n4 = n >> 2;
    int n8 = n >> 3;

    zero_loss_kernel<<<1, 64, 0, stream>>>(out);

    const size_t h_bytes = (size_t)GRID_N * GRID_N * 2;                 // 32 MB
    const size_t rec_bytes = (size_t)n * 8;                             // 128 MB
    const size_t slab_bytes = h_bytes + rec_bytes;                      // 160 MB
    const size_t p7_bytes = (size_t)P7_ROWS * P7_ROW_FLOATS * sizeof(float); // 153.3 MB

    if (ws_size >= slab_bytes) {
        unsigned short* H = (unsigned short*)d_ws;
        unsigned short* R = (unsigned short*)((char*)d_ws + h_bytes);
        build_h_kernel<<<2048, NTHREADS, 0, stream>>>(sdf, H);
        pack_rec_kernel<<<2048, NTHREADS, 0, stream>>>(x, y, R, n4);
        sdf_slab_kernel<<<4096, NTHREADS, 0, stream>>>(R, H, out, n >> 1);
    } else if (ws_size >= p7_bytes) {
        float* P7 = (float*)d_ws;
        dim3 bgrid((P7_BLOCKS * 8 + NTHREADS - 1) / NTHREADS, P7_ROWS);
        build_p7_kernel<<<bgrid, NTHREADS, 0, stream>>>(sdf, P7);
        int nblocks = (n8 + NTHREADS - 1) / NTHREADS;
        sdf_bilinear_p7_kernel<<<nblocks, NTHREADS, 0, stream>>>(x, y, P7, out, n8);
    } else {
        sdf_bilinear_direct_kernel<<<2048, NTHREADS, 0, stream>>>(x, y, sdf, out, n4);
    }
}

// Round 11
// 359.767 us; speedup vs baseline: 1.7666x; 1.5426x over previous
//
#include <hip/hip_runtime.h>
#include <hip/hip_fp16.h>

#define GRID_N 4096
#define NTHREADS 256

// packed15 fp16 layout: each 64B block holds 16 fp16 column-pairs
// (v[r][c], v[r+1][c]) for c = 15b .. 15b+15 (col 15b+15 duplicated as slot 0
// of block b+1). Any bilinear span (c, c+1) with c = 15b+s, s<=14 lives in
// block b -> exactly one 64B line per point; footprint only 71.5 MB.
#define PB 273                       // blocks per row: 15*272+15 = 4095 max col
#define ROW_HALFS (PB * 32)          // 8736 halfs = 17472 B per row
#define NROWS (GRID_N - 1)           // 4095

typedef float f32x4 __attribute__((ext_vector_type(4)));

__device__ __forceinline__ float h2f(unsigned short u) {
    union { __half h; unsigned short u; } cv;
    cv.u = u;
    return __half2float(cv.h);
}
__device__ __forceinline__ unsigned short f2h(float f) {
    union { __half h; unsigned short u; } cv;
    cv.h = __float2half(f);
    return cv.u;
}

__global__ void zero_loss_kernel(float* out) {
    if (threadIdx.x == 0) out[0] = 0.0f;
}

// ---------------- build packed15 grid ----------------
// one block per row r; dword d (= pair slot) covers col = 15*(d>>4) + (d&15).
__global__ __launch_bounds__(NTHREADS) void build_p15_kernel(
    const float* __restrict__ sdf, unsigned int* __restrict__ P)
{
    const int r = blockIdx.x;                 // 0..4094
    const float* row0 = sdf + (size_t)r * GRID_N;
    const float* row1 = row0 + GRID_N;
    unsigned int* prow = P + (size_t)r * (ROW_HALFS / 2);
    const int ndw = PB * 16;                  // 4368 dwords per row
    for (int d = threadIdx.x; d < ndw; d += NTHREADS) {
        int b = d >> 4;
        int s = d & 15;
        int c = 15 * b + s;                   // <= 4095 exactly
        float a = row0[c];
        float e = row1[c];
        unsigned int v = (unsigned int)f2h(a) | ((unsigned int)f2h(e) << 16);
        __builtin_nontemporal_store(v, &prow[d]);
    }
}

// ---------------- main: one 64B line per point, fp16 pairs ----------------
__global__ __launch_bounds__(NTHREADS) void sdf_bilinear_p15_kernel(
    const float* __restrict__ x,
    const float* __restrict__ y,
    const unsigned int* __restrict__ P,   // dword = fp16 pair
    float* __restrict__ out,
    int n8)
{
    const int tid = blockIdx.x * blockDim.x + threadIdx.x;
    const int stride = gridDim.x * blockDim.x;
    float lsum = 0.0f;

    const f32x4* x4 = (const f32x4*)x;
    const f32x4* y4 = (const f32x4*)y;
    float* vals_out = out + 1;

    for (int i = tid; i < n8; i += stride) {
        const int g0 = 2 * i, g1 = 2 * i + 1;
        f32x4 xa = __builtin_nontemporal_load(&x4[g0]);
        f32x4 xb = __builtin_nontemporal_load(&x4[g1]);
        f32x4 ya = __builtin_nontemporal_load(&y4[g0]);
        f32x4 yb = __builtin_nontemporal_load(&y4[g1]);
        float xs[8] = {xa.x, xa.y, xa.z, xa.w, xb.x, xb.y, xb.z, xb.w};
        float ys[8] = {ya.x, ya.y, ya.z, ya.w, yb.x, yb.y, yb.z, yb.w};

        unsigned int d0[8], d1[8];
        float t[8], u[8];
#pragma unroll
        for (int k = 0; k < 8; ++k) {
            float xi = xs[k];
            float yi = ys[k];
            int x1 = min((int)xi, GRID_N - 2);   // inputs >= 0
            int y1 = min((int)yi, GRID_N - 2);
            t[k] = xi - (float)x1;
            u[k] = yi - (float)y1;
            int b = (y1 * 4370) >> 16;           // exact y1/15 for y1 <= 4094
            int s = y1 - 15 * b;                 // 0..14
            const unsigned int* blk = P + (size_t)x1 * (ROW_HALFS / 2) + (b << 4) + s;
            d0[k] = blk[0];   // (v11, v21) — same 64B line
            d1[k] = blk[1];   // (v12, v22) — same 64B line (s<=14, s+1<=15)
        }

        float res[8];
#pragma unroll
        for (int k = 0; k < 8; ++k) {
            float v11 = h2f((unsigned short)d0[k]);
            float v21 = h2f((unsigned short)(d0[k] >> 16));
            float v12 = h2f((unsigned short)d1[k]);
            float v22 = h2f((unsigned short)(d1[k] >> 16));
            float a = v11 + t[k] * (v21 - v11);
            float b2 = v12 + t[k] * (v22 - v12);
            float val = a + u[k] * (b2 - a);
            val = fminf(0.0f, fmaxf(-1000.0f, val));
            res[k] = val;
            lsum += val;
        }

        int base = g0 * 4;
#pragma unroll
        for (int k = 0; k < 8; ++k)
            __builtin_nontemporal_store(res[k], &vals_out[base + k]);
    }

#pragma unroll
    for (int off = 32; off > 0; off >>= 1)
        lsum += __shfl_down(lsum, off);

    __shared__ float wsum[NTHREADS / 64];
    const int lane = threadIdx.x & 63;
    const int wid = threadIdx.x >> 6;
    if (lane == 0) wsum[wid] = lsum;
    __syncthreads();
    if (threadIdx.x == 0) {
        float bsum = 0.0f;
#pragma unroll
        for (int w = 0; w < NTHREADS / 64; ++w) bsum += wsum[w];
        atomicAdd(out, bsum);
    }
}

// ---------------- direct fallback (no workspace) ----------------
__global__ __launch_bounds__(NTHREADS) void sdf_bilinear_direct_kernel(
    const float* __restrict__ x,
    const float* __restrict__ y,
    const float* __restrict__ sdf,
    float* __restrict__ out,
    int n4)
{
    const int tid = blockIdx.x * blockDim.x + threadIdx.x;
    const int stride = gridDim.x * blockDim.x;
    float lsum = 0.0f;
    const f32x4* x4 = (const f32x4*)x;
    const f32x4* y4 = (const f32x4*)y;
    float* vals_out = out + 1;

    for (int i = tid; i < n4; i += stride) {
        f32x4 xv = x4[i];
        f32x4 yv = y4[i];
        float xs[4] = {xv.x, xv.y, xv.z, xv.w};
        float ys[4] = {yv.x, yv.y, yv.z, yv.w};
        float res[4];
#pragma unroll
        for (int k = 0; k < 4; ++k) {
            float xi = xs[k], yi = ys[k];
            int x1 = min((int)xi, GRID_N - 2);
            int y1 = min((int)yi, GRID_N - 2);
            float t = xi - (float)x1;
            float u = yi - (float)y1;
            const float* r1 = sdf + ((size_t)x1 << 12);
            const float* r2 = r1 + GRID_N;
            float v11 = r1[y1], v12 = r1[y1 + 1];
            float v21 = r2[y1], v22 = r2[y1 + 1];
            float a = v11 + t * (v21 - v11);
            float b = v12 + t * (v22 - v12);
            float val = a + u * (b - a);
            val = fminf(0.0f, fmaxf(-1000.0f, val));
            res[k] = val;
            lsum += val;
        }
        int base = i * 4;
        vals_out[base + 0] = res[0];
        vals_out[base + 1] = res[1];
        vals_out[base + 2] = res[2];
        vals_out[base + 3] = res[3];
    }

#pragma unroll
    for (int off = 32; off > 0; off >>= 1)
        lsum += __shfl_down(lsum, off);

    __shared__ float wsum[NTHREADS / 64];
    const int lane = threadIdx.x & 63;
    const int wid = threadIdx.x >> 6;
    if (lane == 0) wsum[wid] = lsum;
    __syncthreads();
    if (threadIdx.x == 0) {
        float bsum = 0.0f;
#pragma unroll
        for (int w = 0; w < NTHREADS / 64; ++w) bsum += wsum[w];
        atomicAdd(out, bsum);
    }
}

extern "C" void kernel_launch(void* const* d_in, const int* in_sizes, int n_in,
                              void* d_out, int out_size, void* d_ws, size_t ws_size,
                              hipStream_t stream) {
    const float* x = (const float*)d_in[0];
    const float* y = (const float*)d_in[1];
    const float* sdf = (const float*)d_in[2];
    float* out = (float*)d_out;
    int n = in_sizes[0];
    int n4 = n >> 2;
    int n8 = n >> 3;

    zero_loss_kernel<<<1, 64, 0, stream>>>(out);

    const size_t p15_bytes = (size_t)NROWS * ROW_HALFS * 2;   // ~71.5 MB

    if (ws_size >= p15_bytes) {
        unsigned int* P = (unsigned int*)d_ws;
        build_p15_kernel<<<NROWS, NTHREADS, 0, stream>>>(sdf, P);
        int nblocks = (n8 + NTHREADS - 1) / NTHREADS;
        sdf_bilinear_p15_kernel<<<nblocks, NTHREADS, 0, stream>>>(x, y, P, out, n8);
    } else {
        sdf_bilinear_direct_kernel<<<2048, NTHREADS, 0, stream>>>(x, y, sdf, out, n4);
    }
}